// Round 8
// baseline (1564.068 us; speedup 1.0000x reference)
//
#include <hip/hip_runtime.h>
#include <math.h>

// StressCapsuleLayer: capsule dynamic routing (3 iters), fused recompute design.
//   x [128][648][16] f32, W [648][32][32][16] f32 -> v [128][32][32] f32
//
// 3 passes over (b,n); u_hat recomputed each pass (never materialized).
//   pass0: c = 1/32 exactly            -> s0 -> v0 = squash(s0)   [pure GEMM]
//   pass1: logit = <u_hat, v0>         -> softmax_j -> s1 -> v1
//   pass2: logit = <u,v0> + <u,v1>     -> softmax_j -> s2 -> v2 = output
//
// R8: R7's 4b+dbuf spilled (WRITE 1.07GB/pass; compiler pins 512-thr blocks
// at 128 VGPR regardless of launch_bounds and spills instead). Revert to the
// proven R6 shape (2 b/thread, ~106 live VGPR) and add a REGISTER-CHEAP
// double buffer: stage tile n+1 in two half-tile windows (ta[4] = 16 regs
// in flight) interleaved with the two compute halves; one barrier per iter.
//   iter: sync | issue A | compute iq0-1 | write A | issue B | compute iq2-3
//         | write B | routing | flip
// Writes go to buf^1 (read finished last iter, guaranteed by the sync).
// PHASE0 accumulates directly into s_acc (x1/32 at store). NC=27 -> grid 216:
// one uniform round on 256 CUs (no ragged tail), 1 block/CU @ 128KB LDS.
// LDS swizzle byte-identical to R5-R7 (verified correct, 0 conflicts).
// Spill detector: WRITE_SIZE >> parts(14MB) per pass => live regs > 128.

#define N_IN 648
#define ELEMS 131072      // 128*32*32 output elements

template <int PHASE>
__global__ __launch_bounds__(512, 2) void caps_pass(
    const float* __restrict__ x,     // [128][648][16]
    const float* __restrict__ W,     // [648][32][32][16]
    const float* __restrict__ v0,    // [128][32][32]  (PHASE>=1)
    const float* __restrict__ v1,    // [128][32][32]  (PHASE==2)
    float* __restrict__ parts,       // [NC][128][32][32] disjoint partial sums
    int nPer)                        // n's per block (648 / NC)
{
  // 2 x 64KB double buffer. W[n]-quad (jj,d,iq) at LDS quad p = c ^ ((c>>6)&7),
  // c = ((d&15)*4+iq)*64 + (d>>4)*32 + jj.   (verified R5-R7: 0 conflicts)
  __shared__ float4 wlds[2][4096];

  const int t = threadIdx.x;
  const int w = t >> 6;   // wave 0..7
  const int l = t & 63;   // lane
  const int j = l & 31;
  const int dblk = l >> 5;

  const int nchunk = blockIdx.x >> 3;   // 0..NC-1
  const int bgroup = blockIdx.x & 7;    // 0..7
  const int n0 = nchunk * nPer;
  const int bA = bgroup * 16 + w * 2;   // this wave's two b's

  // read offsets: quad for kq=(k*4+iq) at byte kq*1024 + offv[kq&7]
  int offv[8];
#pragma unroll
  for (int m = 0; m < 8; ++m) offv[m] = dblk * 512 + 16 * (j ^ m);

  // staging targets: quad g = r*512 + t -> swizzled LDS byte addr
  int stb[8];
#pragma unroll
  for (int r = 0; r < 8; ++r) {
    const int g = r * 512 + t;
    const int jj = g >> 7;
    const int d = (g >> 2) & 31;
    const int iq = g & 3;
    const int c = ((d & 15) * 4 + iq) * 64 + (d >> 4) * 32 + jj;
    stb[r] = 16 * (c ^ ((c >> 6) & 7));
  }

  float s_acc[2][16];
#pragma unroll
  for (int h = 0; h < 2; ++h)
#pragma unroll
    for (int k = 0; k < 16; ++k) s_acc[h][k] = 0.f;

  // prologue: stage tile n0 into buffer 0 (two half-windows, ta[4] live)
  {
    const float4* Wn = (const float4*)(W + (size_t)n0 * 16384);
    float4 ta[4];
#pragma unroll
    for (int r = 0; r < 4; ++r) ta[r] = Wn[r * 512 + t];
#pragma unroll
    for (int r = 0; r < 4; ++r)
      *(float4*)((char*)&wlds[0][0] + stb[r]) = ta[r];
#pragma unroll
    for (int r = 0; r < 4; ++r) ta[r] = Wn[(r + 4) * 512 + t];
#pragma unroll
    for (int r = 0; r < 4; ++r)
      *(float4*)((char*)&wlds[0][0] + stb[r + 4]) = ta[r];
  }

  int cur = 0;
  for (int nn = 0; nn < nPer; ++nn) {
    const int n = n0 + nn;
    __syncthreads();  // buf[cur] staged; all reads of buf[cur^1] done

    const bool more = (nn + 1 < nPer);
    const float4* Wn1 = (const float4*)(W + (size_t)(n + 1) * 16384);
    const char* buf = (const char*)&wlds[cur][0];
    char* nbuf = (char*)&wlds[cur ^ 1][0];

    // wave-uniform x row pointers (SGPR + s_load)
    const float4* xp0 = (const float4*)(x + ((size_t)(bA + 0) * N_IN + n) * 16);
    const float4* xp1 = (const float4*)(x + ((size_t)(bA + 1) * N_IN + n) * 16);

    float uu[2][16];
    if (PHASE != 0) {
#pragma unroll
      for (int k = 0; k < 16; ++k) { uu[0][k] = 0.f; uu[1][k] = 0.f; }
    }
    // accumulation target: PHASE0 writes s_acc directly (no u array live)
#define ACC(hh, kk) ((PHASE == 0) ? s_acc[hh][kk] : uu[hh][kk])

    float4 ta[4];
    // ---- issue staging half A (rounds 0-3) ----
    if (more) {
#pragma unroll
      for (int r = 0; r < 4; ++r) ta[r] = Wn1[r * 512 + t];
    }

    // ---- compute iq = 0,1 ----
#pragma unroll
    for (int iq = 0; iq < 2; ++iq) {
      const float4 xv0 = xp0[iq];
      const float4 xv1 = xp1[iq];
#pragma unroll
      for (int k = 0; k < 16; ++k) {
        const int kq = k * 4 + iq;
        const float4 wq = *(const float4*)(buf + offv[kq & 7] + kq * 1024);
        ACC(0, k) = fmaf(wq.x, xv0.x, ACC(0, k));
        ACC(0, k) = fmaf(wq.y, xv0.y, ACC(0, k));
        ACC(0, k) = fmaf(wq.z, xv0.z, ACC(0, k));
        ACC(0, k) = fmaf(wq.w, xv0.w, ACC(0, k));
        ACC(1, k) = fmaf(wq.x, xv1.x, ACC(1, k));
        ACC(1, k) = fmaf(wq.y, xv1.y, ACC(1, k));
        ACC(1, k) = fmaf(wq.z, xv1.z, ACC(1, k));
        ACC(1, k) = fmaf(wq.w, xv1.w, ACC(1, k));
      }
    }

    // ---- write half A, issue half B ----
    if (more) {
#pragma unroll
      for (int r = 0; r < 4; ++r)
        *(float4*)(nbuf + stb[r]) = ta[r];
#pragma unroll
      for (int r = 0; r < 4; ++r) ta[r] = Wn1[(r + 4) * 512 + t];
    }

    // ---- compute iq = 2,3 ----
#pragma unroll
    for (int iq = 2; iq < 4; ++iq) {
      const float4 xv0 = xp0[iq];
      const float4 xv1 = xp1[iq];
#pragma unroll
      for (int k = 0; k < 16; ++k) {
        const int kq = k * 4 + iq;
        const float4 wq = *(const float4*)(buf + offv[kq & 7] + kq * 1024);
        ACC(0, k) = fmaf(wq.x, xv0.x, ACC(0, k));
        ACC(0, k) = fmaf(wq.y, xv0.y, ACC(0, k));
        ACC(0, k) = fmaf(wq.z, xv0.z, ACC(0, k));
        ACC(0, k) = fmaf(wq.w, xv0.w, ACC(0, k));
        ACC(1, k) = fmaf(wq.x, xv1.x, ACC(1, k));
        ACC(1, k) = fmaf(wq.y, xv1.y, ACC(1, k));
        ACC(1, k) = fmaf(wq.z, xv1.z, ACC(1, k));
        ACC(1, k) = fmaf(wq.w, xv1.w, ACC(1, k));
      }
    }
#undef ACC

    // ---- write half B ----
    if (more) {
#pragma unroll
      for (int r = 0; r < 4; ++r)
        *(float4*)(nbuf + stb[r + 4]) = ta[r];
    }

    // ---- routing (phases 1/2) ----
    if (PHASE != 0) {
#pragma unroll
      for (int h = 0; h < 2; ++h) {
        const int b = bA + h;
        float logit = 0.f;
        {
          const float4* vp = (const float4*)(v0 + (size_t)b * 1024 + j * 32 + dblk * 16);
          float a = 0.f;
#pragma unroll
          for (int q = 0; q < 4; ++q) {
            const float4 vv = vp[q];
            a = fmaf(uu[h][q * 4 + 0], vv.x, a);
            a = fmaf(uu[h][q * 4 + 1], vv.y, a);
            a = fmaf(uu[h][q * 4 + 2], vv.z, a);
            a = fmaf(uu[h][q * 4 + 3], vv.w, a);
          }
          logit += a;
        }
        if (PHASE == 2) {
          const float4* vp = (const float4*)(v1 + (size_t)b * 1024 + j * 32 + dblk * 16);
          float a = 0.f;
#pragma unroll
          for (int q = 0; q < 4; ++q) {
            const float4 vv = vp[q];
            a = fmaf(uu[h][q * 4 + 0], vv.x, a);
            a = fmaf(uu[h][q * 4 + 1], vv.y, a);
            a = fmaf(uu[h][q * 4 + 2], vv.z, a);
            a = fmaf(uu[h][q * 4 + 3], vv.w, a);
          }
          logit += a;
        }
        // full agreement over d: combine the two d-halves
        logit += __shfl_xor(logit, 32);
        // softmax over 32 j's (width-32 butterflies; halves identical)
        float m = logit;
#pragma unroll
        for (int off = 16; off >= 1; off >>= 1) m = fmaxf(m, __shfl_xor(m, off));
        const float e = __expf(logit - m);
        float Z = e;
#pragma unroll
        for (int off = 16; off >= 1; off >>= 1) Z += __shfl_xor(Z, off);
        const float c = e / Z;
#pragma unroll
        for (int k = 0; k < 16; ++k) s_acc[h][k] = fmaf(c, uu[h][k], s_acc[h][k]);
      }
    }

    cur ^= 1;
  }

  // disjoint partial store: parts[chunk][b][j][d]
  float* pbase = parts + (size_t)nchunk * ELEMS;
#pragma unroll
  for (int h = 0; h < 2; ++h) {
    const int b = bA + h;
    float* sp = pbase + (size_t)b * 1024 + j * 32 + dblk * 16;
#pragma unroll
    for (int k = 0; k < 16; ++k)
      sp[k] = (PHASE == 0) ? s_acc[h][k] * 0.03125f : s_acc[h][k];
  }
}

// stage B: sum NC partials, then squash over last dim (32) via width-32 shuffle
__global__ void reduce_squash(const float* __restrict__ parts, int NC,
                              float* __restrict__ v) {
  const int e = blockIdx.x * 256 + threadIdx.x;  // rows of 32 align to half-waves
  float s = 0.f;
  for (int c = 0; c < NC; ++c) s += parts[(size_t)c * ELEMS + e];
  float s2 = s * s;
#pragma unroll
  for (int off = 16; off >= 1; off >>= 1) s2 += __shfl_xor(s2, off);
  const float scale = (s2 / (1.0f + s2)) * rsqrtf(s2 + 1e-7f);
  v[e] = s * scale;
}

extern "C" void kernel_launch(void* const* d_in, const int* in_sizes, int n_in,
                              void* d_out, int out_size, void* d_ws, size_t ws_size,
                              hipStream_t stream) {
  const float* x = (const float*)d_in[0];
  const float* W = (const float*)d_in[1];
  float* out = (float*)d_out;

  float* v0 = (float*)d_ws;            // 131072 f32
  float* v1 = v0 + ELEMS;              // 131072 f32
  float* parts = v1 + ELEMS;           // NC * 131072 f32

  // choose NC (divisor of 648) from available workspace; deterministic since
  // ws_size is fixed. Prefer 27: grid = 8*27 = 216 uniform blocks (1/CU).
  int avail = 0;
  if (ws_size / 4 > 2 * (size_t)ELEMS)
    avail = (int)((ws_size / 4 - 2 * (size_t)ELEMS) / ELEMS);
  const int ladder[] = {27, 24, 18, 12, 9, 8, 6, 4, 3, 2, 1};
  int NC = 1;
  for (int i = 0; i < 11; ++i)
    if (ladder[i] <= avail) { NC = ladder[i]; break; }
  const int nPer = N_IN / NC;

  const dim3 grid(NC * 8);   // 8 b-groups of 16
  const dim3 blk(512);

  caps_pass<0><<<grid, blk, 0, stream>>>(x, W, nullptr, nullptr, parts, nPer);
  reduce_squash<<<512, 256, 0, stream>>>(parts, NC, v0);

  caps_pass<1><<<grid, blk, 0, stream>>>(x, W, v0, nullptr, parts, nPer);
  reduce_squash<<<512, 256, 0, stream>>>(parts, NC, v1);

  caps_pass<2><<<grid, blk, 0, stream>>>(x, W, v0, v1, parts, nPer);
  reduce_squash<<<512, 256, 0, stream>>>(parts, NC, out);
}

// Round 9
// 438.988 us; speedup vs baseline: 3.5629x; 3.5629x over previous
//
#include <hip/hip_runtime.h>
#include <math.h>

// StressCapsuleLayer: capsule dynamic routing (3 iters), fused recompute design.
//   x [128][648][16] f32, W [648][32][32][16] f32 -> v [128][32][32] f32
//
//   pass0: c = 1/32 exactly            -> s0 -> v0 = squash(s0)   [pure GEMM]
//   pass1: logit = <u_hat, v0>         -> softmax_j -> s1 -> v1
//   pass2: logit = <u,v0> + <u,v1>     -> softmax_j -> s2 -> v2 = output
//
// R9: toolchain pins these kernels at 128 VGPR and spills beyond (R7/R8
// evidence). Strategy: PHASE0 has no u[] (direct s_acc accumulation) so 4
// b/thread fits (~105 live): halves ds_read issue (the 52us floor at 2b).
// x staged to LDS (kills x-load hoisting). PHASE1 = R6 + x-LDS (A/B probe);
// PHASE2 = R6-exact control. Spill detector: WRITE_SIZE >> 40MB per pass.

#define N_IN 648
#define ELEMS 131072      // 128*32*32 output elements

// ---------------- phase 0: pure GEMM, 4 b/thread, no u array ----------------
__global__ __launch_bounds__(512, 2) void caps_pass0(
    const float* __restrict__ x, const float* __restrict__ W,
    float* __restrict__ parts, int NC, int nPer)
{
  // W[n]-quad (jj,d,iq) at LDS quad p = c ^ ((c>>6)&7),
  // c = ((d&15)*4+iq)*64 + (d>>4)*32 + jj.  (verified R5-R8: 0 conflicts)
  __shared__ float4 wlds[4096];   // 64KB
  __shared__ float4 xlds[128];    // [32 b][4 iq] = 2KB

  const int t = threadIdx.x;
  const int w = t >> 6, l = t & 63, j = l & 31, dblk = l >> 5;

  int nchunk, bgroup;
  {
    const int bid = blockIdx.x;
    if ((NC & 7) == 0) {
      const int ng = NC >> 3;
      const int xcd = bid & 7;
      const int rem = bid >> 3;          // 0..NC/2-1
      bgroup = rem & 3;
      nchunk = xcd * ng + (rem >> 2);
    } else { nchunk = bid >> 2; bgroup = bid & 3; }
  }
  const int n0 = nchunk * nPer;
  const int b0 = bgroup * 32;
  const int bA = b0 + w * 4;            // this wave's four b's

  int stb[8];
#pragma unroll
  for (int r = 0; r < 8; ++r) {
    const int g = r * 512 + t;
    const int jj = g >> 7;
    const int d = (g >> 2) & 31;
    const int iq = g & 3;
    const int c = ((d & 15) * 4 + iq) * 64 + (d >> 4) * 32 + jj;
    stb[r] = 16 * (c ^ ((c >> 6) & 7));
  }

  float s_acc[4][16];
#pragma unroll
  for (int bb = 0; bb < 4; ++bb)
#pragma unroll
    for (int k = 0; k < 16; ++k) s_acc[bb][k] = 0.f;

  for (int nn = 0; nn < nPer; ++nn) {
    const int n = n0 + nn;
    __syncthreads();
    {
      const float4* Wn = (const float4*)(W + (size_t)n * 16384);
      float4 ta[4];                      // transient: dies before compute
#pragma unroll
      for (int r = 0; r < 4; ++r) ta[r] = Wn[r * 512 + t];
#pragma unroll
      for (int r = 0; r < 4; ++r) *(float4*)((char*)wlds + stb[r]) = ta[r];
#pragma unroll
      for (int r = 0; r < 4; ++r) ta[r] = Wn[(r + 4) * 512 + t];
#pragma unroll
      for (int r = 0; r < 4; ++r) *(float4*)((char*)wlds + stb[r + 4]) = ta[r];
      if (t < 128) {                     // x tile: 32 b x 4 iq
        const int bl = t >> 2, iq = t & 3;
        xlds[t] = *(const float4*)(x + ((size_t)(b0 + bl) * N_IN + n) * 16 + iq * 4);
      }
    }
    __syncthreads();

#pragma unroll
    for (int iq = 0; iq < 4; ++iq) {
      float4 xv[4];
#pragma unroll
      for (int bb = 0; bb < 4; ++bb) xv[bb] = xlds[(w * 4 + bb) * 4 + iq];
      const int off_e = dblk * 512 + 16 * (j ^ iq);        // k even
      const int off_o = dblk * 512 + 16 * (j ^ (iq + 4));  // k odd
#pragma unroll
      for (int k = 0; k < 16; ++k) {
        const int kq = k * 4 + iq;
        const float4 wq = *(const float4*)(
            (const char*)wlds + ((k & 1) ? off_o : off_e) + kq * 1024);
#pragma unroll
        for (int bb = 0; bb < 4; ++bb) {
          s_acc[bb][k] = fmaf(wq.x, xv[bb].x, s_acc[bb][k]);
          s_acc[bb][k] = fmaf(wq.y, xv[bb].y, s_acc[bb][k]);
          s_acc[bb][k] = fmaf(wq.z, xv[bb].z, s_acc[bb][k]);
          s_acc[bb][k] = fmaf(wq.w, xv[bb].w, s_acc[bb][k]);
        }
      }
    }
  }

  float* pbase = parts + (size_t)nchunk * ELEMS;
#pragma unroll
  for (int bb = 0; bb < 4; ++bb) {
    float* sp = pbase + (size_t)(bA + bb) * 1024 + j * 32 + dblk * 16;
#pragma unroll
    for (int k = 0; k < 16; ++k) sp[k] = s_acc[bb][k] * 0.03125f;
  }
}

// ------------- phases 1/2: R6 structure (2 b/thread, single buffer) ---------
// PHASE1 additionally stages x into LDS (A/B probe vs PHASE2 = R6-exact).
template <int PHASE>
__global__ __launch_bounds__(512, 2) void caps_pass(
    const float* __restrict__ x,
    const float* __restrict__ W,
    const float* __restrict__ v0,
    const float* __restrict__ v1,    // PHASE==2 only
    float* __restrict__ parts,
    int NC, int nPer)
{
  __shared__ float4 wlds[4096];
  __shared__ float4 xlds[64];          // PHASE1 only: [16 b][4 iq]

  const int t = threadIdx.x;
  const int w = t >> 6, l = t & 63, j = l & 31, dblk = l >> 5;

  int nchunk, bchunk;
  {
    const int bid = blockIdx.x;
    if ((NC & 7) == 0) {
      const int ng = NC >> 3;
      const int xcd = bid & 7;
      const int rem = bid >> 3;
      bchunk = rem & 7;
      nchunk = xcd * ng + (rem >> 3);
    } else {
      nchunk = bid % NC;
      bchunk = bid / NC;
    }
  }
  const int n0 = nchunk * nPer;
  const int b0 = bchunk * 16;
  const int bA = b0 + w * 2;

  int offv[8];
#pragma unroll
  for (int m = 0; m < 8; ++m) offv[m] = dblk * 512 + 16 * (j ^ m);

  int stb[8];
#pragma unroll
  for (int r = 0; r < 8; ++r) {
    const int g = r * 512 + t;
    const int jj = g >> 7;
    const int d = (g >> 2) & 31;
    const int iq = g & 3;
    const int c = ((d & 15) * 4 + iq) * 64 + (d >> 4) * 32 + jj;
    stb[r] = 16 * (c ^ ((c >> 6) & 7));
  }

  float s_acc[2][16];
#pragma unroll
  for (int h = 0; h < 2; ++h)
#pragma unroll
    for (int k = 0; k < 16; ++k) s_acc[h][k] = 0.f;

  for (int nn = 0; nn < nPer; ++nn) {
    const int n = n0 + nn;

    __syncthreads();
    {
      const float4* Wn = (const float4*)(W + (size_t)n * 16384);
      float4 tmp[8];                    // transient: dead before compute
#pragma unroll
      for (int r = 0; r < 8; ++r) tmp[r] = Wn[r * 512 + t];
#pragma unroll
      for (int r = 0; r < 8; ++r)
        *(float4*)((char*)wlds + stb[r]) = tmp[r];
      if (PHASE == 1 && t < 64) {       // x tile: 16 b x 4 iq
        const int bl = t >> 2, iq = t & 3;
        xlds[t] = *(const float4*)(x + ((size_t)(b0 + bl) * N_IN + n) * 16 + iq * 4);
      }
    }
    __syncthreads();

    const float4* xp0 = (const float4*)(x + ((size_t)(bA + 0) * N_IN + n) * 16);
    const float4* xp1 = (const float4*)(x + ((size_t)(bA + 1) * N_IN + n) * 16);

    float uu[2][16];
#pragma unroll
    for (int k = 0; k < 16; ++k) { uu[0][k] = 0.f; uu[1][k] = 0.f; }

#pragma unroll
    for (int iq = 0; iq < 4; ++iq) {
      float4 xv0, xv1;
      if (PHASE == 1) {
        xv0 = xlds[(w * 2 + 0) * 4 + iq];
        xv1 = xlds[(w * 2 + 1) * 4 + iq];
      } else {
        xv0 = xp0[iq];
        xv1 = xp1[iq];
      }
#pragma unroll
      for (int k = 0; k < 16; ++k) {
        const int kq = k * 4 + iq;
        const float4 wq = *(const float4*)(
            (const char*)wlds + offv[kq & 7] + kq * 1024);
        uu[0][k] = fmaf(wq.x, xv0.x, uu[0][k]);
        uu[0][k] = fmaf(wq.y, xv0.y, uu[0][k]);
        uu[0][k] = fmaf(wq.z, xv0.z, uu[0][k]);
        uu[0][k] = fmaf(wq.w, xv0.w, uu[0][k]);
        uu[1][k] = fmaf(wq.x, xv1.x, uu[1][k]);
        uu[1][k] = fmaf(wq.y, xv1.y, uu[1][k]);
        uu[1][k] = fmaf(wq.z, xv1.z, uu[1][k]);
        uu[1][k] = fmaf(wq.w, xv1.w, uu[1][k]);
      }
    }

#pragma unroll
    for (int h = 0; h < 2; ++h) {
      const int b = bA + h;
      float logit = 0.f;
      {
        const float4* vp = (const float4*)(v0 + (size_t)b * 1024 + j * 32 + dblk * 16);
        float a = 0.f;
#pragma unroll
        for (int q = 0; q < 4; ++q) {
          const float4 vv = vp[q];
          a = fmaf(uu[h][q * 4 + 0], vv.x, a);
          a = fmaf(uu[h][q * 4 + 1], vv.y, a);
          a = fmaf(uu[h][q * 4 + 2], vv.z, a);
          a = fmaf(uu[h][q * 4 + 3], vv.w, a);
        }
        logit += a;
      }
      if (PHASE == 2) {
        const float4* vp = (const float4*)(v1 + (size_t)b * 1024 + j * 32 + dblk * 16);
        float a = 0.f;
#pragma unroll
        for (int q = 0; q < 4; ++q) {
          const float4 vv = vp[q];
          a = fmaf(uu[h][q * 4 + 0], vv.x, a);
          a = fmaf(uu[h][q * 4 + 1], vv.y, a);
          a = fmaf(uu[h][q * 4 + 2], vv.z, a);
          a = fmaf(uu[h][q * 4 + 3], vv.w, a);
        }
        logit += a;
      }
      logit += __shfl_xor(logit, 32);       // full agreement over d
      float m = logit;                      // softmax over 32 j's
#pragma unroll
      for (int off = 16; off >= 1; off >>= 1) m = fmaxf(m, __shfl_xor(m, off));
      const float e = __expf(logit - m);
      float Z = e;
#pragma unroll
      for (int off = 16; off >= 1; off >>= 1) Z += __shfl_xor(Z, off);
      const float c = e / Z;
#pragma unroll
      for (int k = 0; k < 16; ++k) s_acc[h][k] = fmaf(c, uu[h][k], s_acc[h][k]);
    }
  }

  float* pbase = parts + (size_t)nchunk * ELEMS;
#pragma unroll
  for (int h = 0; h < 2; ++h) {
    float* sp = pbase + (size_t)(bA + h) * 1024 + j * 32 + dblk * 16;
#pragma unroll
    for (int k = 0; k < 16; ++k) sp[k] = s_acc[h][k];
  }
}

// stage B: sum NC partials, then squash over last dim (32) via width-32 shuffle
__global__ void reduce_squash(const float* __restrict__ parts, int NC,
                              float* __restrict__ v) {
  const int e = blockIdx.x * 256 + threadIdx.x;
  float s = 0.f;
  for (int c = 0; c < NC; ++c) s += parts[(size_t)c * ELEMS + e];
  float s2 = s * s;
#pragma unroll
  for (int off = 16; off >= 1; off >>= 1) s2 += __shfl_xor(s2, off);
  const float scale = (s2 / (1.0f + s2)) * rsqrtf(s2 + 1e-7f);
  v[e] = s * scale;
}

extern "C" void kernel_launch(void* const* d_in, const int* in_sizes, int n_in,
                              void* d_out, int out_size, void* d_ws, size_t ws_size,
                              hipStream_t stream) {
  const float* x = (const float*)d_in[0];
  const float* W = (const float*)d_in[1];
  float* out = (float*)d_out;

  float* v0 = (float*)d_ws;
  float* v1 = v0 + ELEMS;
  float* parts = v1 + ELEMS;

  int avail = 0;
  if (ws_size / 4 > 2 * (size_t)ELEMS)
    avail = (int)((ws_size / 4 - 2 * (size_t)ELEMS) / ELEMS);
  const int ladder[] = {72, 24, 8, 81, 54, 27, 18, 12, 9, 6, 4, 3, 2, 1};
  int NC = 1;
  for (int i = 0; i < 14; ++i)
    if (ladder[i] <= avail) { NC = ladder[i]; break; }
  const int nPer = N_IN / NC;

  const dim3 blk(512);

  caps_pass0<<<dim3(NC * 4), blk, 0, stream>>>(x, W, parts, NC, nPer);
  reduce_squash<<<512, 256, 0, stream>>>(parts, NC, v0);

  caps_pass<1><<<dim3(NC * 8), blk, 0, stream>>>(x, W, v0, nullptr, parts, NC, nPer);
  reduce_squash<<<512, 256, 0, stream>>>(parts, NC, v1);

  caps_pass<2><<<dim3(NC * 8), blk, 0, stream>>>(x, W, v0, v1, parts, NC, nPer);
  reduce_squash<<<512, 256, 0, stream>>>(parts, NC, out);
}

// Round 10
// 319.865 us; speedup vs baseline: 4.8898x; 1.3724x over previous
//
#include <hip/hip_runtime.h>
#include <math.h>

// StressCapsuleLayer: capsule dynamic routing (3 iters), fused recompute design.
//   x [128][648][16] f32, W [648][32][32][16] f32 -> v [128][32][32] f32
//
//   pass0: c = 1/32 exactly -> s0 -> v0 = squash(s0)   [pure GEMM -> MFMA]
//   pass1: logit = <u_hat, v0>        -> softmax_j -> s1 -> v1
//   pass2: logit = <u,v0> + <u,v1>    -> softmax_j -> s2 -> v2 = output
//
// R10: (a) pass0 rewritten as split-bf16 MFMA GEMM (32x32x16): A = W[n,j]
//   (M=d, K=i), B = x (N=b-tile 32). W/x split hi+lo bf16, 3 MFMAs per tile
//   (drop lo*lo, ~1e-5 rel err). C layout (m74/m101): col=lane&31=b,
//   row=(reg&3)+8*(reg>>2)+4*(lane>>5)=d. Epilogue transposes through LDS so
//   global stores are coalesced. 1 block/CU (129.5KB arena), grid NC*4=256.
// (b) phases = R6-exact structure (136us, no spill) + UNEVEN n-chunks with
//   NC=64 -> grid 512 = exactly 2 blocks/CU (R9's 157us had a 1.5x tail:
//   576 blocks over 512 slots). XCD decode dropped (W is L3-served).
// Spill detector: WRITE_SIZE >> ~34MB per pass.

#define N_IN 648
#define ELEMS 131072      // 128*32*32 output elements

typedef __attribute__((ext_vector_type(8))) short short8v;
typedef __attribute__((ext_vector_type(16))) float f32x16;

// split float into hi/lo bf16 pair-packed words: hw/lw hold 2 bf16 (a in low,
// b in high). hi = truncate-to-bf16, lo = bf16(residual): product error ~2^-16.
__device__ __forceinline__ void split2(float a, float b, unsigned& hw, unsigned& lw) {
  const unsigned ab = __float_as_uint(a), bb = __float_as_uint(b);
  const unsigned ah = ab & 0xFFFF0000u, bh = bb & 0xFFFF0000u;
  const float al = a - __uint_as_float(ah);
  const float bl = b - __uint_as_float(bh);
  hw = bh | (ab >> 16);
  lw = (__float_as_uint(bl) & 0xFFFF0000u) | (__float_as_uint(al) >> 16);
}

// ---------------- pass 0: split-bf16 MFMA GEMM ----------------
__global__ __launch_bounds__(512, 1) void caps_pass0_mfma(
    const float* __restrict__ x, const float* __restrict__ W,
    float* __restrict__ parts, int NC)
{
  // arena: Whi[j][d][16B slot x2] @0 (32KB), Wlo @32768, xhi @65536, xlo @66560.
  // epilogue reuses whole arena as [32 b][1036 f32] transpose buffer.
  __shared__ __align__(16) char arena[132608];

  const int t = threadIdx.x;
  const int w = t >> 6, l = t & 63;
  const int b32 = l & 31, half = l >> 5;

  const int nchunk = blockIdx.x >> 2;
  const int btile = blockIdx.x & 3;
  const int n0 = (N_IN * nchunk) / NC;
  const int n1 = (N_IN * (nchunk + 1)) / NC;
  const int b0 = btile * 32;

  // frag read offsets; XOR-slot so banks spread 4-way, content half == lane>>5
  const int aoff = b32 * 32 + 16 * (half ^ ((b32 >> 2) & 1));
  const int boff = 65536 + b32 * 32 + 16 * (half ^ ((b32 >> 2) & 1));

  f32x16 acc[4];
#pragma unroll
  for (int q = 0; q < 4; ++q) acc[q] = (f32x16)(0.0f);

  const int jS = t >> 4;        // staging: this thread's j
  const int dp = (t & 15) * 2;  // staging: d-pair base

  for (int n = n0; n < n1; ++n) {
    __syncthreads();  // previous tile's frag reads done
    {
      const float4* Wg = (const float4*)(W + (size_t)n * 16384 + jS * 512 + dp * 16);
#pragma unroll
      for (int dd = 0; dd < 2; ++dd) {   // one d-row at a time (keeps regs low)
        const int d = dp + dd;
        const float4 a0 = Wg[dd * 4 + 0], a1 = Wg[dd * 4 + 1];
        const float4 a2 = Wg[dd * 4 + 2], a3 = Wg[dd * 4 + 3];
        float row[16] = {a0.x, a0.y, a0.z, a0.w, a1.x, a1.y, a1.z, a1.w,
                         a2.x, a2.y, a2.z, a2.w, a3.x, a3.y, a3.z, a3.w};
        unsigned hw[8], lw[8];
#pragma unroll
        for (int e = 0; e < 8; ++e) split2(row[2 * e], row[2 * e + 1], hw[e], lw[e]);
        const int xb = (d >> 2) & 1;
        const int base_ = jS * 1024 + d * 32;
        *(uint4*)(arena + base_ + 16 * (0 ^ xb)) = uint4{hw[0], hw[1], hw[2], hw[3]};
        *(uint4*)(arena + base_ + 16 * (1 ^ xb)) = uint4{hw[4], hw[5], hw[6], hw[7]};
        *(uint4*)(arena + 32768 + base_ + 16 * (0 ^ xb)) = uint4{lw[0], lw[1], lw[2], lw[3]};
        *(uint4*)(arena + 32768 + base_ + 16 * (1 ^ xb)) = uint4{lw[4], lw[5], lw[6], lw[7]};
      }
    }
    if (t < 128) {  // x tile: b = t>>2, iq = t&3 (4 i's each)
      const int bb = t >> 2, iq = t & 3;
      const float4 xv = *(const float4*)(x + ((size_t)(b0 + bb) * N_IN + n) * 16 + iq * 4);
      unsigned h0, l0, h1, l1;
      split2(xv.x, xv.y, h0, l0);
      split2(xv.z, xv.w, h1, l1);
      const int slot = 16 * ((iq >> 1) ^ ((bb >> 2) & 1)) + (iq & 1) * 8;
      *(uint2*)(arena + 65536 + bb * 32 + slot) = uint2{h0, h1};
      *(uint2*)(arena + 66560 + bb * 32 + slot) = uint2{l0, l1};
    }
    __syncthreads();  // tile staged

    const short8v bhi = *(const short8v*)(arena + boff);
    const short8v blo = *(const short8v*)(arena + boff + 1024);
#pragma unroll
    for (int q = 0; q < 4; ++q) {
      const int j = w * 4 + q;
      const short8v ahi = *(const short8v*)(arena + j * 1024 + aoff);
      const short8v alo = *(const short8v*)(arena + 32768 + j * 1024 + aoff);
      acc[q] = __builtin_amdgcn_mfma_f32_32x32x16_bf16(ahi, bhi, acc[q], 0, 0, 0);
      acc[q] = __builtin_amdgcn_mfma_f32_32x32x16_bf16(ahi, blo, acc[q], 0, 0, 0);
      acc[q] = __builtin_amdgcn_mfma_f32_32x32x16_bf16(alo, bhi, acc[q], 0, 0, 0);
    }
  }

  // epilogue: scatter acc into arena [b][1036 f32], read back coalesced
  __syncthreads();
#pragma unroll
  for (int q = 0; q < 4; ++q) {
    const int j = w * 4 + q;
#pragma unroll
    for (int g = 0; g < 4; ++g) {   // regs g*4..g*4+3 = d = g*8 + 4*half + 0..3
      float4 v4;
      v4.x = acc[q][g * 4 + 0] * 0.03125f;
      v4.y = acc[q][g * 4 + 1] * 0.03125f;
      v4.z = acc[q][g * 4 + 2] * 0.03125f;
      v4.w = acc[q][g * 4 + 3] * 0.03125f;
      *(float4*)(arena + (b32 * 1036 + j * 32 + g * 8 + 4 * half) * 4) = v4;
    }
  }
  __syncthreads();
  {
    float* pb = parts + (size_t)nchunk * ELEMS + (size_t)b0 * 1024;
    const int rb = t >> 4, c16 = t & 15;
#pragma unroll
    for (int q = 0; q < 16; ++q) {
      const int e4 = c16 + q * 16;
      const float4 v4 = *(const float4*)(arena + (rb * 1036 + e4 * 4) * 4);
      *(float4*)(pb + rb * 1024 + e4 * 4) = v4;
    }
  }
}

// ------------- phases 1/2: R6-exact structure, uneven chunks -------------
template <int PHASE>
__global__ __launch_bounds__(512, 2) void caps_pass(
    const float* __restrict__ x, const float* __restrict__ W,
    const float* __restrict__ v0, const float* __restrict__ v1,
    float* __restrict__ parts, int NC)
{
  // W[n]-quad (jj,d,iq) at LDS quad p = c ^ ((c>>6)&7),
  // c = ((d&15)*4+iq)*64 + (d>>4)*32 + jj.  (verified R5-R9: 0 conflicts)
  __shared__ float4 wlds[4096];

  const int t = threadIdx.x;
  const int w = t >> 6, l = t & 63, j = l & 31, dblk = l >> 5;

  const int nchunk = blockIdx.x >> 3;
  const int bchunk = blockIdx.x & 7;
  const int n0 = (N_IN * nchunk) / NC;
  const int n1 = (N_IN * (nchunk + 1)) / NC;
  const int bA = bchunk * 16 + w * 2;

  int offv[8];
#pragma unroll
  for (int m = 0; m < 8; ++m) offv[m] = dblk * 512 + 16 * (j ^ m);

  int stb[8];
#pragma unroll
  for (int r = 0; r < 8; ++r) {
    const int g = r * 512 + t;
    const int jj = g >> 7;
    const int d = (g >> 2) & 31;
    const int iq = g & 3;
    const int c = ((d & 15) * 4 + iq) * 64 + (d >> 4) * 32 + jj;
    stb[r] = 16 * (c ^ ((c >> 6) & 7));
  }

  float s_acc[2][16];
#pragma unroll
  for (int h = 0; h < 2; ++h)
#pragma unroll
    for (int k = 0; k < 16; ++k) s_acc[h][k] = 0.f;

  for (int n = n0; n < n1; ++n) {
    __syncthreads();
    {
      const float4* Wn = (const float4*)(W + (size_t)n * 16384);
      float4 tmp[8];  // transient: dead before compute
#pragma unroll
      for (int r = 0; r < 8; ++r) tmp[r] = Wn[r * 512 + t];
#pragma unroll
      for (int r = 0; r < 8; ++r)
        *(float4*)((char*)wlds + stb[r]) = tmp[r];
    }
    __syncthreads();

    const float4* xp0 = (const float4*)(x + ((size_t)(bA + 0) * N_IN + n) * 16);
    const float4* xp1 = (const float4*)(x + ((size_t)(bA + 1) * N_IN + n) * 16);

    float uu[2][16];
#pragma unroll
    for (int k = 0; k < 16; ++k) { uu[0][k] = 0.f; uu[1][k] = 0.f; }

#pragma unroll
    for (int iq = 0; iq < 4; ++iq) {
      const float4 xv0 = xp0[iq];
      const float4 xv1 = xp1[iq];
#pragma unroll
      for (int k = 0; k < 16; ++k) {
        const int kq = k * 4 + iq;
        const float4 wq = *(const float4*)(
            (const char*)wlds + offv[kq & 7] + kq * 1024);
        uu[0][k] = fmaf(wq.x, xv0.x, uu[0][k]);
        uu[0][k] = fmaf(wq.y, xv0.y, uu[0][k]);
        uu[0][k] = fmaf(wq.z, xv0.z, uu[0][k]);
        uu[0][k] = fmaf(wq.w, xv0.w, uu[0][k]);
        uu[1][k] = fmaf(wq.x, xv1.x, uu[1][k]);
        uu[1][k] = fmaf(wq.y, xv1.y, uu[1][k]);
        uu[1][k] = fmaf(wq.z, xv1.z, uu[1][k]);
        uu[1][k] = fmaf(wq.w, xv1.w, uu[1][k]);
      }
    }

#pragma unroll
    for (int h = 0; h < 2; ++h) {
      const int b = bA + h;
      float logit = 0.f;
      {
        const float4* vp = (const float4*)(v0 + (size_t)b * 1024 + j * 32 + dblk * 16);
        float a = 0.f;
#pragma unroll
        for (int q = 0; q < 4; ++q) {
          const float4 vv = vp[q];
          a = fmaf(uu[h][q * 4 + 0], vv.x, a);
          a = fmaf(uu[h][q * 4 + 1], vv.y, a);
          a = fmaf(uu[h][q * 4 + 2], vv.z, a);
          a = fmaf(uu[h][q * 4 + 3], vv.w, a);
        }
        logit += a;
      }
      if (PHASE == 2) {
        const float4* vp = (const float4*)(v1 + (size_t)b * 1024 + j * 32 + dblk * 16);
        float a = 0.f;
#pragma unroll
        for (int q = 0; q < 4; ++q) {
          const float4 vv = vp[q];
          a = fmaf(uu[h][q * 4 + 0], vv.x, a);
          a = fmaf(uu[h][q * 4 + 1], vv.y, a);
          a = fmaf(uu[h][q * 4 + 2], vv.z, a);
          a = fmaf(uu[h][q * 4 + 3], vv.w, a);
        }
        logit += a;
      }
      logit += __shfl_xor(logit, 32);   // full agreement over d
      float m = logit;                  // softmax over 32 j's
#pragma unroll
      for (int off = 16; off >= 1; off >>= 1) m = fmaxf(m, __shfl_xor(m, off));
      const float e = __expf(logit - m);
      float Z = e;
#pragma unroll
      for (int off = 16; off >= 1; off >>= 1) Z += __shfl_xor(Z, off);
      const float c = e / Z;
#pragma unroll
      for (int k = 0; k < 16; ++k) s_acc[h][k] = fmaf(c, uu[h][k], s_acc[h][k]);
    }
  }

  float* pbase = parts + (size_t)nchunk * ELEMS;
#pragma unroll
  for (int h = 0; h < 2; ++h) {
    float* sp = pbase + (size_t)(bA + h) * 1024 + j * 32 + dblk * 16;
#pragma unroll
    for (int k = 0; k < 16; ++k) sp[k] = s_acc[h][k];
  }
}

// stage B: sum NC partials, then squash over last dim (32) via width-32 shuffle
__global__ void reduce_squash(const float* __restrict__ parts, int NC,
                              float* __restrict__ v) {
  const int e = blockIdx.x * 256 + threadIdx.x;
  float s = 0.f;
  for (int c = 0; c < NC; ++c) s += parts[(size_t)c * ELEMS + e];
  float s2 = s * s;
#pragma unroll
  for (int off = 16; off >= 1; off >>= 1) s2 += __shfl_xor(s2, off);
  const float scale = (s2 / (1.0f + s2)) * rsqrtf(s2 + 1e-7f);
  v[e] = s * scale;
}

extern "C" void kernel_launch(void* const* d_in, const int* in_sizes, int n_in,
                              void* d_out, int out_size, void* d_ws, size_t ws_size,
                              hipStream_t stream) {
  const float* x = (const float*)d_in[0];
  const float* W = (const float*)d_in[1];
  float* out = (float*)d_out;

  float* v0 = (float*)d_ws;
  float* v1 = v0 + ELEMS;
  float* parts = v1 + ELEMS;

  // uneven n-chunking works for ANY NC; pick min(64, what fits). NC=64 gives
  // pass0 grid 256 (1/CU) and phase grid 512 (2/CU) -- both exactly balanced.
  int avail = 0;
  if (ws_size / 4 > 2 * (size_t)ELEMS)
    avail = (int)((ws_size / 4 - 2 * (size_t)ELEMS) / ELEMS);
  int NC = avail < 1 ? 1 : (avail > 64 ? 64 : avail);

  const dim3 blk(512);

  caps_pass0_mfma<<<dim3(NC * 4), blk, 0, stream>>>(x, W, parts, NC);
  reduce_squash<<<512, 256, 0, stream>>>(parts, NC, v0);

  caps_pass<1><<<dim3(NC * 8), blk, 0, stream>>>(x, W, v0, nullptr, parts, NC);
  reduce_squash<<<512, 256, 0, stream>>>(parts, NC, v1);

  caps_pass<2><<<dim3(NC * 8), blk, 0, stream>>>(x, W, v0, v1, parts, NC);
  reduce_squash<<<512, 256, 0, stream>>>(parts, NC, out);
}

// Round 11
// 266.089 us; speedup vs baseline: 5.8780x; 1.2021x over previous
//
#include <hip/hip_runtime.h>
#include <math.h>

// StressCapsuleLayer: capsule dynamic routing (3 iters), fused recompute design.
//   x [128][648][16] f32, W [648][32][32][16] f32 -> v [128][32][32] f32
//
//   pass0: c = 1/32 exactly -> s0 -> v0 = squash(s0)   [split-bf16 MFMA GEMM]
//   pass1: logit = <u_hat, v0>        -> softmax_j -> s1 -> v1
//   pass2: logit = <u,v0> + <u,v1>    -> softmax_j -> s2 -> v2 = output
//
// R11: phases ported to the MFMA structure (R10 evidence: pass0_mfma does the
// same GEMM volume in <=~30us vs 130us FMA-phase; LDS reads/lane/n drop
// 64 -> ~12). Register wall (u + s_acc > 128) broken by the identity
//   s[b,j,:] = sum_n W[n,j] . (c[b,n,j] * x[b,n])
// -> s accumulates DIRECTLY in MFMA accs (64 VGPR); u_hat is transient:
//   logit pass: per j: 3 MFMAs -> u (16 regs), dot with v0/v1 (f32 gathers,
//     b = lane&31), discard; write logit to lg[j][b^j] (conflict-free).
//   softmax: per (jj,b) thread slot, width-32 butterflies, c overwrites lg.
//   s pass: per j: B = split-bf16(c_j * x) (x reconstructed from bf16 hi+lo
//     regs), 3 MFMAs into persistent acc.
// All fragment layouts / staging / epilogue byte-identical to R10-validated
// pass0. 4 barriers/n-tile. Arena 129.5KB -> 1 block/CU, grid NC*4.
// Spill detector: WRITE_SIZE >> ~34MB per pass.

#define N_IN 648
#define ELEMS 131072      // 128*32*32 output elements

typedef __attribute__((ext_vector_type(8))) short short8v;
typedef __attribute__((ext_vector_type(16))) float f32x16;

// split float into hi/lo bf16 pair-packed words: hw/lw hold 2 bf16 (a in low,
// b in high). hi = truncate-to-bf16, lo = bf16(residual): product error ~2^-16.
__device__ __forceinline__ void split2(float a, float b, unsigned& hw, unsigned& lw) {
  const unsigned ab = __float_as_uint(a), bb = __float_as_uint(b);
  const unsigned ah = ab & 0xFFFF0000u, bh = bb & 0xFFFF0000u;
  const float al = a - __uint_as_float(ah);
  const float bl = b - __uint_as_float(bh);
  hw = bh | (ab >> 16);
  lw = (__float_as_uint(bl) & 0xFFFF0000u) | (__float_as_uint(al) >> 16);
}

union U8 { uint4 u; short8v s; };

// ---- shared staging helpers (R10-validated layout) ----
// arena: Whi @0 (32KB), Wlo @32768, xhi @65536 (1KB), xlo @66560 (1KB),
// lg/c @69632 (4KB, phases only). Epilogue reuses arena as [32][1036] f32.

__device__ __forceinline__ void stage_tile(char* arena, const float* __restrict__ x,
                                           const float* __restrict__ W,
                                           int n, int b0, int t) {
  const int jS = t >> 4;        // this thread's j
  const int dp = (t & 15) * 2;  // d-pair base
  const float4* Wg = (const float4*)(W + (size_t)n * 16384 + jS * 512 + dp * 16);
#pragma unroll
  for (int dd = 0; dd < 2; ++dd) {
    const int d = dp + dd;
    const float4 a0 = Wg[dd * 4 + 0], a1 = Wg[dd * 4 + 1];
    const float4 a2 = Wg[dd * 4 + 2], a3 = Wg[dd * 4 + 3];
    float row[16] = {a0.x, a0.y, a0.z, a0.w, a1.x, a1.y, a1.z, a1.w,
                     a2.x, a2.y, a2.z, a2.w, a3.x, a3.y, a3.z, a3.w};
    unsigned hw[8], lw[8];
#pragma unroll
    for (int e = 0; e < 8; ++e) split2(row[2 * e], row[2 * e + 1], hw[e], lw[e]);
    const int xb = (d >> 2) & 1;
    const int base_ = jS * 1024 + d * 32;
    *(uint4*)(arena + base_ + 16 * (0 ^ xb)) = uint4{hw[0], hw[1], hw[2], hw[3]};
    *(uint4*)(arena + base_ + 16 * (1 ^ xb)) = uint4{hw[4], hw[5], hw[6], hw[7]};
    *(uint4*)(arena + 32768 + base_ + 16 * (0 ^ xb)) = uint4{lw[0], lw[1], lw[2], lw[3]};
    *(uint4*)(arena + 32768 + base_ + 16 * (1 ^ xb)) = uint4{lw[4], lw[5], lw[6], lw[7]};
  }
  if (t < 128) {  // x tile: b = t>>2, iq = t&3 (4 i's each)
    const int bb = t >> 2, iq = t & 3;
    const float4 xv = *(const float4*)(x + ((size_t)(b0 + bb) * N_IN + n) * 16 + iq * 4);
    unsigned h0, l0, h1, l1;
    split2(xv.x, xv.y, h0, l0);
    split2(xv.z, xv.w, h1, l1);
    const int slot = 16 * ((iq >> 1) ^ ((bb >> 2) & 1)) + (iq & 1) * 8;
    *(uint2*)(arena + 65536 + bb * 32 + slot) = uint2{h0, h1};
    *(uint2*)(arena + 66560 + bb * 32 + slot) = uint2{l0, l1};
  }
}

// epilogue: scatter acc (C layout col=lane&31=b, row=(reg&3)+8*(reg>>2)+4*half
// = d) into arena [b][1036 f32], read back coalesced into parts.
__device__ __forceinline__ void store_parts(char* arena, float* __restrict__ parts,
                                            const f32x16* acc, float scale,
                                            int nchunk, int b0, int t) {
  const int w = t >> 6, l = t & 63;
  const int b32 = l & 31, half = l >> 5;
  __syncthreads();
#pragma unroll
  for (int q = 0; q < 4; ++q) {
    const int j = w * 4 + q;
#pragma unroll
    for (int g = 0; g < 4; ++g) {
      float4 v4;
      v4.x = acc[q][g * 4 + 0] * scale;
      v4.y = acc[q][g * 4 + 1] * scale;
      v4.z = acc[q][g * 4 + 2] * scale;
      v4.w = acc[q][g * 4 + 3] * scale;
      *(float4*)(arena + (b32 * 1036 + j * 32 + g * 8 + 4 * half) * 4) = v4;
    }
  }
  __syncthreads();
  float* pb = parts + (size_t)nchunk * ELEMS + (size_t)b0 * 1024;
  const int rb = t >> 4, c16 = t & 15;
#pragma unroll
  for (int q = 0; q < 16; ++q) {
    const int e4 = c16 + q * 16;
    const float4 v4 = *(const float4*)(arena + (rb * 1036 + e4 * 4) * 4);
    *(float4*)(pb + rb * 1024 + e4 * 4) = v4;
  }
}

// ---------------- pass 0: split-bf16 MFMA GEMM (R10-validated) ----------------
__global__ __launch_bounds__(512, 1) void caps_pass0_mfma(
    const float* __restrict__ x, const float* __restrict__ W,
    float* __restrict__ parts, int NC)
{
  __shared__ __align__(16) char arena[132608];

  const int t = threadIdx.x;
  const int w = t >> 6, l = t & 63;
  const int b32 = l & 31, half = l >> 5;

  const int nchunk = blockIdx.x >> 2;
  const int btile = blockIdx.x & 3;
  const int n0 = (N_IN * nchunk) / NC;
  const int n1 = (N_IN * (nchunk + 1)) / NC;
  const int b0 = btile * 32;

  const int aoff = b32 * 32 + 16 * (half ^ ((b32 >> 2) & 1));
  const int boff = 65536 + aoff;

  f32x16 acc[4];
#pragma unroll
  for (int q = 0; q < 4; ++q) acc[q] = (f32x16)(0.0f);

  for (int n = n0; n < n1; ++n) {
    __syncthreads();
    stage_tile(arena, x, W, n, b0, t);
    __syncthreads();

    const short8v bhi = *(const short8v*)(arena + boff);
    const short8v blo = *(const short8v*)(arena + boff + 1024);
#pragma unroll
    for (int q = 0; q < 4; ++q) {
      const int j = w * 4 + q;
      const short8v ahi = *(const short8v*)(arena + j * 1024 + aoff);
      const short8v alo = *(const short8v*)(arena + 32768 + j * 1024 + aoff);
      acc[q] = __builtin_amdgcn_mfma_f32_32x32x16_bf16(ahi, bhi, acc[q], 0, 0, 0);
      acc[q] = __builtin_amdgcn_mfma_f32_32x32x16_bf16(ahi, blo, acc[q], 0, 0, 0);
      acc[q] = __builtin_amdgcn_mfma_f32_32x32x16_bf16(alo, bhi, acc[q], 0, 0, 0);
    }
  }
  store_parts(arena, parts, acc, 0.03125f, nchunk, b0, t);
}

// ------------- phases 1/2: MFMA with c folded into B-operand -------------
template <int PHASE>
__global__ __launch_bounds__(512, 1) void caps_phase_mfma(
    const float* __restrict__ x, const float* __restrict__ W,
    const float* __restrict__ v0, const float* __restrict__ v1,
    float* __restrict__ parts, int NC)
{
  __shared__ __align__(16) char arena[132608];

  const int t = threadIdx.x;
  const int w = t >> 6, l = t & 63;
  const int b32 = l & 31, half = l >> 5;

  const int nchunk = blockIdx.x >> 2;
  const int btile = blockIdx.x & 3;
  const int n0 = (N_IN * nchunk) / NC;
  const int n1 = (N_IN * (nchunk + 1)) / NC;
  const int b0 = btile * 32;
  const int bg = b0 + b32;            // this lane's b (global)

  const int aoff = b32 * 32 + 16 * (half ^ ((b32 >> 2) & 1));
  const int boff = 65536 + aoff;

  f32x16 accs[4];
#pragma unroll
  for (int q = 0; q < 4; ++q) accs[q] = (f32x16)(0.0f);

  for (int n = n0; n < n1; ++n) {
    __syncthreads();   // previous tile's LDS consumers done
    stage_tile(arena, x, W, n, b0, t);
    __syncthreads();

    const short8v bhi = *(const short8v*)(arena + boff);
    const short8v blo = *(const short8v*)(arena + boff + 1024);

    // ---- logit pass: u transient per j, dot with v, write lg[j][b^j] ----
#pragma unroll
    for (int q = 0; q < 4; ++q) {
      const int j = w * 4 + q;
      const short8v ahi = *(const short8v*)(arena + j * 1024 + aoff);
      const short8v alo = *(const short8v*)(arena + 32768 + j * 1024 + aoff);
      f32x16 ut = (f32x16)(0.0f);
      ut = __builtin_amdgcn_mfma_f32_32x32x16_bf16(ahi, bhi, ut, 0, 0, 0);
      ut = __builtin_amdgcn_mfma_f32_32x32x16_bf16(ahi, blo, ut, 0, 0, 0);
      ut = __builtin_amdgcn_mfma_f32_32x32x16_bf16(alo, bhi, ut, 0, 0, 0);
      // reg r = g*4+e  <->  d = g*8 + 4*half + e
      const float* vp0 = v0 + (size_t)bg * 1024 + j * 32 + 4 * half;
      float a = 0.f;
#pragma unroll
      for (int g = 0; g < 4; ++g) {
        const float4 vv = *(const float4*)(vp0 + g * 8);
        a = fmaf(ut[g * 4 + 0], vv.x, a);
        a = fmaf(ut[g * 4 + 1], vv.y, a);
        a = fmaf(ut[g * 4 + 2], vv.z, a);
        a = fmaf(ut[g * 4 + 3], vv.w, a);
      }
      if (PHASE == 2) {
        const float* vp1 = v1 + (size_t)bg * 1024 + j * 32 + 4 * half;
#pragma unroll
        for (int g = 0; g < 4; ++g) {
          const float4 vv = *(const float4*)(vp1 + g * 8);
          a = fmaf(ut[g * 4 + 0], vv.x, a);
          a = fmaf(ut[g * 4 + 1], vv.y, a);
          a = fmaf(ut[g * 4 + 2], vv.z, a);
          a = fmaf(ut[g * 4 + 3], vv.w, a);
        }
      }
      a += __shfl_xor(a, 32);           // combine d-halves
      if (l < 32)                        // conflict-free: banks = b^j distinct
        *(float*)(arena + 69632 + (j * 32 + ((b32 ^ j) & 31)) * 4) = a;
    }
    __syncthreads();

    // ---- softmax over j per b: thread owns slot (jj, b), 2 rounds ----
    {
      const int jj = t & 31;
#pragma unroll
      for (int r = 0; r < 2; ++r) {
        const int b = r * 16 + (t >> 5);
        float* slot = (float*)(arena + 69632 + (jj * 32 + ((b ^ jj) & 31)) * 4);
        float lg = *slot;
        float m = lg;
#pragma unroll
        for (int off = 16; off >= 1; off >>= 1) m = fmaxf(m, __shfl_xor(m, off));
        const float e = __expf(lg - m);
        float Z = e;
#pragma unroll
        for (int off = 16; off >= 1; off >>= 1) Z += __shfl_xor(Z, off);
        *slot = e / Z;                  // c overwrites lg (own slot only)
      }
    }
    __syncthreads();

    // ---- s pass: B = split-bf16(c_j * x), accumulate into persistent acc ----
    float xf[8];                        // reconstruct x f32 from bf16 hi+lo
#pragma unroll
    for (int e = 0; e < 8; ++e) {
      const unsigned hb = ((unsigned)(unsigned short)bhi[e]) << 16;
      const unsigned lb = ((unsigned)(unsigned short)blo[e]) << 16;
      xf[e] = __uint_as_float(hb) + __uint_as_float(lb);
    }
#pragma unroll
    for (int q = 0; q < 4; ++q) {
      const int j = w * 4 + q;
      const float cj = *(const float*)(arena + 69632 + (j * 32 + ((b32 ^ j) & 31)) * 4);
      U8 yh, yl;
#pragma unroll
      for (int e = 0; e < 4; ++e) {
        unsigned hw, lw;
        split2(cj * xf[2 * e], cj * xf[2 * e + 1], hw, lw);
        ((unsigned*)&yh.u)[e] = hw;
        ((unsigned*)&yl.u)[e] = lw;
      }
      const short8v ahi = *(const short8v*)(arena + j * 1024 + aoff);
      const short8v alo = *(const short8v*)(arena + 32768 + j * 1024 + aoff);
      accs[q] = __builtin_amdgcn_mfma_f32_32x32x16_bf16(ahi, yh.s, accs[q], 0, 0, 0);
      accs[q] = __builtin_amdgcn_mfma_f32_32x32x16_bf16(ahi, yl.s, accs[q], 0, 0, 0);
      accs[q] = __builtin_amdgcn_mfma_f32_32x32x16_bf16(alo, yh.s, accs[q], 0, 0, 0);
    }
  }
  store_parts(arena, parts, accs, 1.0f, nchunk, b0, t);
}

// stage B: sum NC partials, then squash over last dim (32) via width-32 shuffle
__global__ void reduce_squash(const float* __restrict__ parts, int NC,
                              float* __restrict__ v) {
  const int e = blockIdx.x * 256 + threadIdx.x;
  float s = 0.f;
  for (int c = 0; c < NC; ++c) s += parts[(size_t)c * ELEMS + e];
  float s2 = s * s;
#pragma unroll
  for (int off = 16; off >= 1; off >>= 1) s2 += __shfl_xor(s2, off);
  const float scale = (s2 / (1.0f + s2)) * rsqrtf(s2 + 1e-7f);
  v[e] = s * scale;
}

extern "C" void kernel_launch(void* const* d_in, const int* in_sizes, int n_in,
                              void* d_out, int out_size, void* d_ws, size_t ws_size,
                              hipStream_t stream) {
  const float* x = (const float*)d_in[0];
  const float* W = (const float*)d_in[1];
  float* out = (float*)d_out;

  float* v0 = (float*)d_ws;
  float* v1 = v0 + ELEMS;
  float* parts = v1 + ELEMS;

  // uneven n-chunking works for ANY NC; pick min(64, what fits). NC=64 ->
  // grid 256 = 1 block/CU for all three passes (129.5KB LDS arena each).
  int avail = 0;
  if (ws_size / 4 > 2 * (size_t)ELEMS)
    avail = (int)((ws_size / 4 - 2 * (size_t)ELEMS) / ELEMS);
  int NC = avail < 1 ? 1 : (avail > 64 ? 64 : avail);

  const dim3 blk(512);

  caps_pass0_mfma<<<dim3(NC * 4), blk, 0, stream>>>(x, W, parts, NC);
  reduce_squash<<<512, 256, 0, stream>>>(parts, NC, v0);

  caps_phase_mfma<1><<<dim3(NC * 4), blk, 0, stream>>>(x, W, v0, nullptr, parts, NC);
  reduce_squash<<<512, 256, 0, stream>>>(parts, NC, v1);

  caps_phase_mfma<2><<<dim3(NC * 4), blk, 0, stream>>>(x, W, v0, v1, parts, NC);
  reduce_squash<<<512, 256, 0, stream>>>(parts, NC, out);
}

// Round 12
// 202.914 us; speedup vs baseline: 7.7080x; 1.3113x over previous
//
#include <hip/hip_runtime.h>
#include <hip/hip_fp16.h>
#include <math.h>

// StressCapsuleLayer: capsule dynamic routing (3 iters), fused recompute design.
//   x [128][648][16] f32, W [648][32][32][16] f32 -> v [128][32][32] f32
//
//   pass0: c = 1/32 -> s0 -> v0 = squash(s0)            [split-bf16 MFMA GEMM]
//   pass1: logit = <u_hat, v0>          -> softmax_j -> s1 -> v1
//   pass2: logit = <u, v0+v1> (linear!) -> softmax_j -> s2 -> v2 = output
//
// R12: R11 phases were 80% stalled (MfmaUtil 5.5, VALU 15) — prime suspect:
// n-invariant v0/v1 re-gathered uncoalesced from global EVERY n-tile with a
// dependent dot. Changes:
//  1. v hoisted to LDS as f16 ONCE per block (64KB, [j][half][rot b] layout,
//     element order = MFMA C-reg d-order so the dot is unpack+16 FMA).
//  2. logits2 = <u, v0+v1> -> reduce_squash emits vsum; phases unified (one
//     v array, no second gather path).
//  3. Conflict-free frags: A/B read at l*16 (64-lane contiguous 1KB/j);
//     staging writes 16-lane contiguous 256B runs. (R11: 2.95M conflicts)
// Spill detector: WRITE_SIZE >> ~34MB per pass.

#define N_IN 648
#define ELEMS 131072      // 128*32*32 output elements

// arena offsets (phase kernel)
#define WHI 0
#define WLO 32768
#define XHI 65536
#define XLO 66560
#define VLD 67584
#define LG  133120
#define ARENA_PH 137216
#define ARENA_P0 132608   // pass0: sized by epilogue reuse [32][1036] f32

typedef __attribute__((ext_vector_type(8))) short short8v;
typedef __attribute__((ext_vector_type(16))) float f32x16;

union U8 { uint4 u; short8v s; };
union HU { __half h; unsigned short u; };

// split float into hi/lo bf16 pair-packed words (a low half, b high half)
__device__ __forceinline__ void split2(float a, float b, unsigned& hw, unsigned& lw) {
  const unsigned ab = __float_as_uint(a), bb = __float_as_uint(b);
  const unsigned ah = ab & 0xFFFF0000u, bh = bb & 0xFFFF0000u;
  const float al = a - __uint_as_float(ah);
  const float bl = b - __uint_as_float(bh);
  hw = bh | (ab >> 16);
  lw = (__float_as_uint(bl) & 0xFFFF0000u) | (__float_as_uint(al) >> 16);
}

__device__ __forceinline__ unsigned short f2h(float f) {
  HU x; x.h = __float2half(f); return x.u;
}
__device__ __forceinline__ float h2f(unsigned short u) {
  HU x; x.u = u; return __half2float(x.h);
}
__device__ __forceinline__ unsigned pkh(float a, float b) {
  return (unsigned)f2h(a) | ((unsigned)f2h(b) << 16);
}

// stage W[n] (split-bf16) + x tile into arena. Frag layout: lane l reads its
// 16B at j*1024 + l*16 (A) / XHI + l*16 (B) -> 64-lane contiguous, 0 conflict.
// A content: lane (d=l&31, h=l>>5) = W[j][d][i=h*8..+8]; B: x[b=l&31][i=h*8..+8].
__device__ __forceinline__ void stage_tile(char* arena, const float* __restrict__ x,
                                           const float* __restrict__ W,
                                           int n, int b0, int t) {
  const int jS = t >> 4, m = t & 15;
  const float* Wr = W + (size_t)n * 16384 + jS * 512;
#pragma unroll
  for (int dd = 0; dd < 2; ++dd) {
    const int d = m + dd * 16;
    const float4* rp = (const float4*)(Wr + d * 16);
    const float4 a0 = rp[0], a1 = rp[1], a2 = rp[2], a3 = rp[3];
    float row[16] = {a0.x, a0.y, a0.z, a0.w, a1.x, a1.y, a1.z, a1.w,
                     a2.x, a2.y, a2.z, a2.w, a3.x, a3.y, a3.z, a3.w};
    unsigned hw[8], lw[8];
#pragma unroll
    for (int e = 0; e < 8; ++e) split2(row[2 * e], row[2 * e + 1], hw[e], lw[e]);
    char* bH = arena + WHI + jS * 1024 + d * 16;
    char* bL = arena + WLO + jS * 1024 + d * 16;
    *(uint4*)(bH)       = uint4{hw[0], hw[1], hw[2], hw[3]};
    *(uint4*)(bH + 512) = uint4{hw[4], hw[5], hw[6], hw[7]};
    *(uint4*)(bL)       = uint4{lw[0], lw[1], lw[2], lw[3]};
    *(uint4*)(bL + 512) = uint4{lw[4], lw[5], lw[6], lw[7]};
  }
  if (t < 64) {
    const int b = t & 31, h = t >> 5;
    const float4* xp = (const float4*)(x + ((size_t)(b0 + b) * N_IN + n) * 16 + h * 8);
    const float4 x0 = xp[0], x1 = xp[1];
    unsigned hw[4], lw[4];
    split2(x0.x, x0.y, hw[0], lw[0]);
    split2(x0.z, x0.w, hw[1], lw[1]);
    split2(x1.x, x1.y, hw[2], lw[2]);
    split2(x1.z, x1.w, hw[3], lw[3]);
    *(uint4*)(arena + XHI + t * 16) = uint4{hw[0], hw[1], hw[2], hw[3]};
    *(uint4*)(arena + XLO + t * 16) = uint4{lw[0], lw[1], lw[2], lw[3]};
  }
}

// epilogue: scatter acc (C layout: col=lane&31=b, d = (r&3)+8*(r>>2)+4*half)
// into arena [b][1036 f32], read back coalesced into parts.
__device__ __forceinline__ void store_parts(char* arena, float* __restrict__ parts,
                                            const f32x16* acc, float scale,
                                            int nchunk, int b0, int t) {
  const int w = t >> 6, l = t & 63;
  const int b32 = l & 31, half = l >> 5;
  __syncthreads();
#pragma unroll
  for (int q = 0; q < 4; ++q) {
    const int j = w * 4 + q;
#pragma unroll
    for (int g = 0; g < 4; ++g) {
      float4 v4;
      v4.x = acc[q][g * 4 + 0] * scale;
      v4.y = acc[q][g * 4 + 1] * scale;
      v4.z = acc[q][g * 4 + 2] * scale;
      v4.w = acc[q][g * 4 + 3] * scale;
      *(float4*)(arena + (b32 * 1036 + j * 32 + g * 8 + 4 * half) * 4) = v4;
    }
  }
  __syncthreads();
  float* pb = parts + (size_t)nchunk * ELEMS + (size_t)b0 * 1024;
  const int rb = t >> 4, c16 = t & 15;
#pragma unroll
  for (int q = 0; q < 16; ++q) {
    const int e4 = c16 + q * 16;
    const float4 v4 = *(const float4*)(arena + (rb * 1036 + e4 * 4) * 4);
    *(float4*)(pb + rb * 1024 + e4 * 4) = v4;
  }
}

// ---------------- pass 0: split-bf16 MFMA GEMM ----------------
__global__ __launch_bounds__(512, 1) void caps_pass0_mfma(
    const float* __restrict__ x, const float* __restrict__ W,
    float* __restrict__ parts, int NC)
{
  __shared__ __align__(16) char arena[ARENA_P0];
  const int t = threadIdx.x;
  const int w = t >> 6, l = t & 63;
  const int nchunk = blockIdx.x >> 2, btile = blockIdx.x & 3;
  const int n0 = (N_IN * nchunk) / NC;
  const int n1 = (N_IN * (nchunk + 1)) / NC;
  const int b0 = btile * 32;

  f32x16 acc[4];
#pragma unroll
  for (int q = 0; q < 4; ++q) acc[q] = (f32x16)(0.0f);

  for (int n = n0; n < n1; ++n) {
    __syncthreads();
    stage_tile(arena, x, W, n, b0, t);
    __syncthreads();
    const short8v bhi = *(const short8v*)(arena + XHI + l * 16);
    const short8v blo = *(const short8v*)(arena + XLO + l * 16);
#pragma unroll
    for (int q = 0; q < 4; ++q) {
      const int j = w * 4 + q;
      const short8v ahi = *(const short8v*)(arena + WHI + j * 1024 + l * 16);
      const short8v alo = *(const short8v*)(arena + WLO + j * 1024 + l * 16);
      acc[q] = __builtin_amdgcn_mfma_f32_32x32x16_bf16(ahi, bhi, acc[q], 0, 0, 0);
      acc[q] = __builtin_amdgcn_mfma_f32_32x32x16_bf16(ahi, blo, acc[q], 0, 0, 0);
      acc[q] = __builtin_amdgcn_mfma_f32_32x32x16_bf16(alo, bhi, acc[q], 0, 0, 0);
    }
  }
  store_parts(arena, parts, acc, 0.03125f, nchunk, b0, t);
}

// ------------- phases 1/2 (unified): v-in-LDS, c folded into B -------------
__global__ __launch_bounds__(512, 1) void caps_phase_mfma(
    const float* __restrict__ x, const float* __restrict__ W,
    const float* __restrict__ v,      // v0 (phase1) or v0+v1 (phase2)
    float* __restrict__ parts, int NC)
{
  __shared__ __align__(16) char arena[ARENA_PH];
  const int t = threadIdx.x;
  const int w = t >> 6, l = t & 63;
  const int b32 = l & 31, half = l >> 5;
  const int nchunk = blockIdx.x >> 2, btile = blockIdx.x & 3;
  const int n0 = (N_IN * nchunk) / NC;
  const int n1 = (N_IN * (nchunk + 1)) / NC;
  const int b0 = btile * 32;

  // ---- stage v ONCE (n-invariant): f16 [j][h][rot(b)], d-order = C-reg order
#pragma unroll
  for (int r = 0; r < 2; ++r) {
    const int p = r * 512 + t;
    const int b = p >> 5, jj = p & 31;
    const float* gv = v + (size_t)(b0 + b) * 1024 + jj * 32;
    char* vb = arena + VLD + jj * 2048 + ((b + jj) & 31) * 32;
#pragma unroll
    for (int h = 0; h < 2; ++h) {
      const float4 g0 = *(const float4*)(gv + h * 4 + 0);
      const float4 g1 = *(const float4*)(gv + h * 4 + 8);
      const float4 g2 = *(const float4*)(gv + h * 4 + 16);
      const float4 g3 = *(const float4*)(gv + h * 4 + 24);
      *(uint4*)(vb + h * 1024) =
          uint4{pkh(g0.x, g0.y), pkh(g0.z, g0.w), pkh(g1.x, g1.y), pkh(g1.z, g1.w)};
      *(uint4*)(vb + h * 1024 + 16) =
          uint4{pkh(g2.x, g2.y), pkh(g2.z, g2.w), pkh(g3.x, g3.y), pkh(g3.z, g3.w)};
    }
  }

  f32x16 accs[4];
#pragma unroll
  for (int q = 0; q < 4; ++q) accs[q] = (f32x16)(0.0f);

  for (int n = n0; n < n1; ++n) {
    __syncthreads();   // prev consumers done (also covers v-stage on iter 0)
    stage_tile(arena, x, W, n, b0, t);
    __syncthreads();

    const short8v bhi = *(const short8v*)(arena + XHI + l * 16);
    const short8v blo = *(const short8v*)(arena + XLO + l * 16);

    // ---- logit pass: transient u per j, dot with v (LDS f16), write lg ----
#pragma unroll
    for (int q = 0; q < 4; ++q) {
      const int j = w * 4 + q;
      const short8v ahi = *(const short8v*)(arena + WHI + j * 1024 + l * 16);
      const short8v alo = *(const short8v*)(arena + WLO + j * 1024 + l * 16);
      f32x16 ut = (f32x16)(0.0f);
      ut = __builtin_amdgcn_mfma_f32_32x32x16_bf16(ahi, bhi, ut, 0, 0, 0);
      ut = __builtin_amdgcn_mfma_f32_32x32x16_bf16(ahi, blo, ut, 0, 0, 0);
      ut = __builtin_amdgcn_mfma_f32_32x32x16_bf16(alo, bhi, ut, 0, 0, 0);
      const char* vp = arena + VLD + j * 2048 + half * 1024 + ((b32 + j) & 31) * 32;
      const uint4 va = *(const uint4*)(vp);
      const uint4 vb4 = *(const uint4*)(vp + 16);
      const unsigned wd[8] = {va.x, va.y, va.z, va.w, vb4.x, vb4.y, vb4.z, vb4.w};
      float a = 0.f;
#pragma unroll
      for (int k = 0; k < 16; ++k) {
        const unsigned short us = (k & 1) ? (unsigned short)(wd[k >> 1] >> 16)
                                          : (unsigned short)(wd[k >> 1] & 0xFFFF);
        a = fmaf(ut[k], h2f(us), a);
      }
      a += __shfl_xor(a, 32);           // combine d-halves
      if (l < 32)                        // banks = b^j distinct: conflict-free
        *(float*)(arena + LG + (j * 32 + ((b32 ^ j) & 31)) * 4) = a;
    }
    __syncthreads();

    // ---- softmax over j per b (2 rounds of 16 b) ----
    {
      const int jj = t & 31;
#pragma unroll
      for (int r = 0; r < 2; ++r) {
        const int b = r * 16 + (t >> 5);
        float* slot = (float*)(arena + LG + (jj * 32 + ((b ^ jj) & 31)) * 4);
        float lgv = *slot;
        float mx = lgv;
#pragma unroll
        for (int off = 16; off >= 1; off >>= 1) mx = fmaxf(mx, __shfl_xor(mx, off));
        const float e = __expf(lgv - mx);
        float Z = e;
#pragma unroll
        for (int off = 16; off >= 1; off >>= 1) Z += __shfl_xor(Z, off);
        *slot = e / Z;
      }
    }
    __syncthreads();

    // ---- s pass: B = split-bf16(c_j * x), accumulate into persistent acc ----
    float xf[8];
#pragma unroll
    for (int e = 0; e < 8; ++e) {
      const unsigned hb = ((unsigned)(unsigned short)bhi[e]) << 16;
      const unsigned lb = ((unsigned)(unsigned short)blo[e]) << 16;
      xf[e] = __uint_as_float(hb) + __uint_as_float(lb);
    }
#pragma unroll
    for (int q = 0; q < 4; ++q) {
      const int j = w * 4 + q;
      const float cj = *(const float*)(arena + LG + (j * 32 + ((b32 ^ j) & 31)) * 4);
      U8 yh, yl;
      split2(cj * xf[0], cj * xf[1], ((unsigned*)&yh.u)[0], ((unsigned*)&yl.u)[0]);
      split2(cj * xf[2], cj * xf[3], ((unsigned*)&yh.u)[1], ((unsigned*)&yl.u)[1]);
      split2(cj * xf[4], cj * xf[5], ((unsigned*)&yh.u)[2], ((unsigned*)&yl.u)[2]);
      split2(cj * xf[6], cj * xf[7], ((unsigned*)&yh.u)[3], ((unsigned*)&yl.u)[3]);
      const short8v ahi = *(const short8v*)(arena + WHI + j * 1024 + l * 16);
      const short8v alo = *(const short8v*)(arena + WLO + j * 1024 + l * 16);
      accs[q] = __builtin_amdgcn_mfma_f32_32x32x16_bf16(ahi, yh.s, accs[q], 0, 0, 0);
      accs[q] = __builtin_amdgcn_mfma_f32_32x32x16_bf16(ahi, yl.s, accs[q], 0, 0, 0);
      accs[q] = __builtin_amdgcn_mfma_f32_32x32x16_bf16(alo, yh.s, accs[q], 0, 0, 0);
    }
  }
  store_parts(arena, parts, accs, 1.0f, nchunk, b0, t);
}

// stage B: sum NC partials, squash; optionally add previous v (vsum = v0+v1)
__global__ void reduce_squash(const float* __restrict__ parts, int NC,
                              float* __restrict__ out,
                              const float* __restrict__ addprev) {
  const int e = blockIdx.x * 256 + threadIdx.x;
  float s = 0.f;
  for (int c = 0; c < NC; ++c) s += parts[(size_t)c * ELEMS + e];
  float s2 = s * s;
#pragma unroll
  for (int off = 16; off >= 1; off >>= 1) s2 += __shfl_xor(s2, off);
  const float scale = (s2 / (1.0f + s2)) * rsqrtf(s2 + 1e-7f);
  const float val = s * scale;
  out[e] = addprev ? (addprev[e] + val) : val;
}

extern "C" void kernel_launch(void* const* d_in, const int* in_sizes, int n_in,
                              void* d_out, int out_size, void* d_ws, size_t ws_size,
                              hipStream_t stream) {
  const float* x = (const float*)d_in[0];
  const float* W = (const float*)d_in[1];
  float* out = (float*)d_out;

  float* v0 = (float*)d_ws;
  float* vsum = v0 + ELEMS;
  float* parts = vsum + ELEMS;

  int avail = 0;
  if (ws_size / 4 > 2 * (size_t)ELEMS)
    avail = (int)((ws_size / 4 - 2 * (size_t)ELEMS) / ELEMS);
  int NC = avail < 1 ? 1 : (avail > 64 ? 64 : avail);

  const dim3 blk(512);

  caps_pass0_mfma<<<dim3(NC * 4), blk, 0, stream>>>(x, W, parts, NC);
  reduce_squash<<<512, 256, 0, stream>>>(parts, NC, v0, nullptr);

  caps_phase_mfma<<<dim3(NC * 4), blk, 0, stream>>>(x, W, v0, parts, NC);
  reduce_squash<<<512, 256, 0, stream>>>(parts, NC, vsum, v0);  // v0 + v1

  caps_phase_mfma<<<dim3(NC * 4), blk, 0, stream>>>(x, W, vsum, parts, NC);
  reduce_squash<<<512, 256, 0, stream>>>(parts, NC, out, nullptr);
}

// Round 13
// 155.067 us; speedup vs baseline: 10.0864x; 1.3086x over previous
//
#include <hip/hip_runtime.h>
#include <hip/hip_fp16.h>
#include <math.h>

// StressCapsuleLayer: capsule dynamic routing (3 iters), fused recompute design.
//   x [128][648][16] f32, W [648][32][32][16] f32 -> v [128][32][32] f32
//
//   pass0: c = 1/32 -> s0 -> v0 = squash(s0)            [f16 MFMA GEMM]
//   pass1: logit = <u_hat, v0>          -> softmax_j -> s1 -> v1
//   pass2: logit = <u, v0+v1> (linear)  -> softmax_j -> s2 -> v2 = output
//
// R13 (on R12's 61us/phase, 65% stalled):
//  1. W/x as f16 (mfma_f32_32x32x16_f16): staging bytes 64K->32K/tile, no
//     split2 VALU, MFMAs 24->8 per tile/wave. Error budget: f16 2^-11 adds
//     ~2-4e-3; threshold 1.36e-2 (was 3.9e-3 measured).
//  2. LDS double-buffer W/x + reg split-pump prefetch (tA[4]=16 regs, reused;
//     peak ~115 VGPR, spill-safe): global latency hidden under compute.
//     3 barriers/iter (was 4).
//  3. v-LDS relaid as per-j lane-indexed 1KB word-blocks: v reads 64-lane
//     contiguous (R12 had 16-way conflicts, 925K). x kept f32 in word-blocks
//     (exact c*x; conflict-free reads).
//  4. XCD-aware bid decode: 4 b-tile sharers of an n-chunk -> same XCD
//     (bid = q*32 + btile*8 + r, nchunk = q*8+r), W L2-localized.
// Spill detector: WRITE_SIZE >> ~34MB/pass.

#define N_IN 648
#define ELEMS 131072      // 128*32*32 output elements

// phase arena: WF[2] @0/32768 (32K each), XF32[2] @65536/+2048 (2K each),
// VLD @69632 (64K), LG @135168 (4K). Epilogue reuse needs 132608 <= 139264.
#define XF_OFF 65536
#define VLD 69632
#define LG 135168
#define ARENA_PH 139264
#define ARENA_P0 132608   // pass0: sized by epilogue reuse [32][1036] f32

typedef __attribute__((ext_vector_type(8))) _Float16 f16x8;
typedef __attribute__((ext_vector_type(16))) float f32x16;

union F16U { uint4 u; f16x8 f; };
union HU { __half h; unsigned short us; };

__device__ __forceinline__ unsigned pkh(float a, float b) {
  HU x, y; x.h = __float2half(a); y.h = __float2half(b);
  return (unsigned)x.us | ((unsigned)y.us << 16);
}
__device__ __forceinline__ float h2f(unsigned short u) {
  HU x; x.us = u; return __half2float(x.h);
}

// cvt one W row (16 f32 in r[0..3]) to f16 and write its two frag slots:
// slot (d,h=0) = i0..7 at jS*1024 + d*16; slot (d,h=1) = i8..15 at +512.
__device__ __forceinline__ void writeW(char* wbuf, int jS, int d, const float4* r) {
  uint4 h0, h1;
  h0.x = pkh(r[0].x, r[0].y); h0.y = pkh(r[0].z, r[0].w);
  h0.z = pkh(r[1].x, r[1].y); h0.w = pkh(r[1].z, r[1].w);
  h1.x = pkh(r[2].x, r[2].y); h1.y = pkh(r[2].z, r[2].w);
  h1.z = pkh(r[3].x, r[3].y); h1.w = pkh(r[3].z, r[3].w);
  *(uint4*)(wbuf + jS * 1024 + d * 16) = h0;
  *(uint4*)(wbuf + jS * 1024 + 512 + d * 16) = h1;
}
__device__ __forceinline__ void loadW(float4* r, const float* __restrict__ W,
                                      int n, int jS, int d) {
  const float4* rp = (const float4*)(W + (size_t)n * 16384 + jS * 512 + d * 16);
  r[0] = rp[0]; r[1] = rp[1]; r[2] = rp[2]; r[3] = rp[3];
}

// epilogue: scatter acc (C layout: col=lane&31=b, d=(r&3)+8*(r>>2)+4*half)
// into arena [b][1036 f32], read back coalesced into parts.
__device__ __forceinline__ void store_parts(char* arena, float* __restrict__ parts,
                                            const f32x16* acc, float scale,
                                            int nchunk, int b0, int t) {
  const int w = t >> 6, l = t & 63;
  const int b32 = l & 31, half = l >> 5;
  __syncthreads();
#pragma unroll
  for (int q = 0; q < 4; ++q) {
    const int j = w * 4 + q;
#pragma unroll
    for (int g = 0; g < 4; ++g) {
      float4 v4;
      v4.x = acc[q][g * 4 + 0] * scale;
      v4.y = acc[q][g * 4 + 1] * scale;
      v4.z = acc[q][g * 4 + 2] * scale;
      v4.w = acc[q][g * 4 + 3] * scale;
      *(float4*)(arena + (b32 * 1036 + j * 32 + g * 8 + 4 * half) * 4) = v4;
    }
  }
  __syncthreads();
  float* pb = parts + (size_t)nchunk * ELEMS + (size_t)b0 * 1024;
  const int rb = t >> 4, c16 = t & 15;
#pragma unroll
  for (int q = 0; q < 16; ++q) {
    const int e4 = c16 + q * 16;
    const float4 v4 = *(const float4*)(arena + (rb * 1036 + e4 * 4) * 4);
    *(float4*)(pb + rb * 1024 + e4 * 4) = v4;
  }
}

// XCD-aware decode: nchunk = q*8+r, bid = q*32 + btile*8 + r -> bid&7 = r,
// so all 4 btile-sharers of a nchunk land on one XCD (round-robin dispatch).
__device__ __forceinline__ void decode_bid(int bid, int NC, int& nchunk, int& btile) {
  if ((NC & 7) == 0) {
    const int r = bid & 7;
    btile = (bid >> 3) & 3;
    nchunk = (bid >> 5) * 8 + r;
  } else {
    nchunk = bid >> 2;
    btile = bid & 3;
  }
}

// ---------------- pass 0: f16 MFMA GEMM, dbuf + full-tile prefetch ----------
__global__ __launch_bounds__(512, 1) void caps_pass0_mfma(
    const float* __restrict__ x, const float* __restrict__ W,
    float* __restrict__ parts, int NC)
{
  __shared__ __align__(16) char arena[ARENA_P0];
  const int t = threadIdx.x;
  const int w = t >> 6, l = t & 63;
  const int jS = t >> 4, m = t & 15;
  int nchunk, btile;
  decode_bid(blockIdx.x, NC, nchunk, btile);
  const int n0 = (N_IN * nchunk) / NC;
  const int n1 = (N_IN * (nchunk + 1)) / NC;
  const int b0 = btile * 32;

  f32x16 acc[4];
#pragma unroll
  for (int q = 0; q < 4; ++q) acc[q] = (f32x16)(0.0f);

  // prologue: stage tile n0 into buffer 0
  {
    float4 rA[4], rB[4];
    loadW(rA, W, n0, jS, m);
    loadW(rB, W, n0, jS, m + 16);
    writeW(arena, jS, m, rA);
    writeW(arena, jS, m + 16, rB);
    if (t < 64) {
      const float4* xp = (const float4*)(x + ((size_t)(b0 + (t & 31)) * N_IN + n0) * 16 + (t >> 5) * 8);
      *(float4*)(arena + XF_OFF + t * 16) = xp[0];
      *(float4*)(arena + XF_OFF + 1024 + t * 16) = xp[1];
    }
  }

  int cur = 0;
  for (int n = n0; n < n1; ++n) {
    __syncthreads();                    // buf[cur] visible
    const char* wf = arena + cur * 32768;
    const char* xb = arena + XF_OFF + cur * 2048;
    char* nwf = arena + (cur ^ 1) * 32768;
    char* nxb = arena + XF_OFF + (cur ^ 1) * 2048;
    const bool more = (n + 1 < n1);

    float4 tA[4], tB[4], xt0, xt1;
    if (more) {
      loadW(tA, W, n + 1, jS, m);
      loadW(tB, W, n + 1, jS, m + 16);
      if (t < 64) {
        const float4* xp = (const float4*)(x + ((size_t)(b0 + (t & 31)) * N_IN + n + 1) * 16 + (t >> 5) * 8);
        xt0 = xp[0]; xt1 = xp[1];
      }
    }

    const float4 xw0 = *(const float4*)(xb + l * 16);
    const float4 xw1 = *(const float4*)(xb + 1024 + l * 16);
    F16U bf;
    bf.u = uint4{pkh(xw0.x, xw0.y), pkh(xw0.z, xw0.w),
                 pkh(xw1.x, xw1.y), pkh(xw1.z, xw1.w)};
#pragma unroll
    for (int q = 0; q < 4; ++q) {
      const int j = w * 4 + q;
      const f16x8 af = *(const f16x8*)(wf + j * 1024 + l * 16);
      acc[q] = __builtin_amdgcn_mfma_f32_32x32x16_f16(af, bf.f, acc[q], 0, 0, 0);
    }

    if (more) {
      writeW(nwf, jS, m, tA);
      writeW(nwf, jS, m + 16, tB);
      if (t < 64) {
        *(float4*)(nxb + t * 16) = xt0;
        *(float4*)(nxb + 1024 + t * 16) = xt1;
      }
    }
    cur ^= 1;
  }
  store_parts(arena, parts, acc, 0.03125f, nchunk, b0, t);
}

// ------------- phases 1/2 (unified): f16 MFMA, dbuf, split-pump -------------
__global__ __launch_bounds__(512, 1) void caps_phase_mfma(
    const float* __restrict__ x, const float* __restrict__ W,
    const float* __restrict__ v,      // v0 (phase1) or v0+v1 (phase2)
    float* __restrict__ parts, int NC)
{
  __shared__ __align__(16) char arena[ARENA_PH];
  const int t = threadIdx.x;
  const int w = t >> 6, l = t & 63;
  const int b32 = l & 31;
  const int jS = t >> 4, m = t & 15;
  int nchunk, btile;
  decode_bid(blockIdx.x, NC, nchunk, btile);
  const int n0 = (N_IN * nchunk) / NC;
  const int n1 = (N_IN * (nchunk + 1)) / NC;
  const int b0 = btile * 32;

  // ---- stage v ONCE: per-j two 1KB lane-indexed word blocks (f16 pairs).
  // word w, lane slot s = 32h + b holds f16 v[b][j][d] for d = 16w+4h+e and
  // 16w+8+4h+e (e=0..3) -> matches ut[k] order (k = 8w..8w+7).
#pragma unroll
  for (int r2 = 0; r2 < 2; ++r2) {
    const int j = t >> 4, b = (t & 15) + r2 * 16;
    const float4* gv = (const float4*)(v + (size_t)(b0 + b) * 1024 + j * 32);
    float4 g[8];
#pragma unroll
    for (int q = 0; q < 8; ++q) g[q] = gv[q];
#pragma unroll
    for (int h = 0; h < 2; ++h)
#pragma unroll
      for (int wd = 0; wd < 2; ++wd) {
        const float4 a = g[4 * wd + h];        // d = 16wd+4h+0..3
        const float4 bb = g[4 * wd + h + 2];   // d = 16wd+8+4h+0..3
        *(uint4*)(arena + VLD + j * 2048 + wd * 1024 + (h * 32 + b) * 16) =
            uint4{pkh(a.x, a.y), pkh(a.z, a.w), pkh(bb.x, bb.y), pkh(bb.z, bb.w)};
      }
  }

  // prologue: stage tile n0 into buffer 0
  {
    float4 rA[4], rB[4];
    loadW(rA, W, n0, jS, m);
    loadW(rB, W, n0, jS, m + 16);
    writeW(arena, jS, m, rA);
    writeW(arena, jS, m + 16, rB);
    if (t < 64) {
      const float4* xp = (const float4*)(x + ((size_t)(b0 + (t & 31)) * N_IN + n0) * 16 + (t >> 5) * 8);
      *(float4*)(arena + XF_OFF + t * 16) = xp[0];
      *(float4*)(arena + XF_OFF + 1024 + t * 16) = xp[1];
    }
  }

  f32x16 acc[4];
#pragma unroll
  for (int q = 0; q < 4; ++q) acc[q] = (f32x16)(0.0f);

  int cur = 0;
  for (int n = n0; n < n1; ++n) {
    __syncthreads();                    // buf[cur] + v visible; lg free
    const char* wf = arena + cur * 32768;
    const char* xb = arena + XF_OFF + cur * 2048;
    char* nwf = arena + (cur ^ 1) * 32768;
    char* nxb = arena + XF_OFF + (cur ^ 1) * 2048;
    const bool more = (n + 1 < n1);

    // split-pump prefetch, batch A (16 regs) + x
    float4 tA[4], xt0, xt1;
    if (more) {
      loadW(tA, W, n + 1, jS, m);
      if (t < 64) {
        const float4* xp = (const float4*)(x + ((size_t)(b0 + (t & 31)) * N_IN + n + 1) * 16 + (t >> 5) * 8);
        xt0 = xp[0]; xt1 = xp[1];
      }
    }

    // B frag (x f32 words -> f16)
    const float4 xw0 = *(const float4*)(xb + l * 16);
    const float4 xw1 = *(const float4*)(xb + 1024 + l * 16);
    F16U bf;
    bf.u = uint4{pkh(xw0.x, xw0.y), pkh(xw0.z, xw0.w),
                 pkh(xw1.x, xw1.y), pkh(xw1.z, xw1.w)};

    // ---- logit pass: transient u per j, dot with v (conflict-free), lg ----
#pragma unroll
    for (int q = 0; q < 4; ++q) {
      const int j = w * 4 + q;
      const f16x8 af = *(const f16x8*)(wf + j * 1024 + l * 16);
      f32x16 ut = (f32x16)(0.0f);
      ut = __builtin_amdgcn_mfma_f32_32x32x16_f16(af, bf.f, ut, 0, 0, 0);
      const uint4 va = *(const uint4*)(arena + VLD + j * 2048 + l * 16);
      const uint4 vb = *(const uint4*)(arena + VLD + j * 2048 + 1024 + l * 16);
      const unsigned wd[8] = {va.x, va.y, va.z, va.w, vb.x, vb.y, vb.z, vb.w};
      float a = 0.f;
#pragma unroll
      for (int k = 0; k < 16; ++k) {
        const unsigned short us = (k & 1) ? (unsigned short)(wd[k >> 1] >> 16)
                                          : (unsigned short)(wd[k >> 1] & 0xFFFF);
        a = fmaf(ut[k], h2f(us), a);
      }
      a += __shfl_xor(a, 32);           // combine d-halves
      if (l < 32)                        // banks = b^j distinct: conflict-free
        *(float*)(arena + LG + (j * 32 + ((b32 ^ j) & 31)) * 4) = a;
    }
    __syncthreads();                    // logits complete

    // ---- softmax over j per b (2 rounds of 16 b) ----
    {
      const int jj = t & 31;
#pragma unroll
      for (int r = 0; r < 2; ++r) {
        const int b = r * 16 + (t >> 5);
        float* slot = (float*)(arena + LG + (jj * 32 + ((b ^ jj) & 31)) * 4);
        float lgv = *slot;
        float mx = lgv;
#pragma unroll
        for (int off = 16; off >= 1; off >>= 1) mx = fmaxf(mx, __shfl_xor(mx, off));
        const float e = __expf(lgv - mx);
        float Z = e;
#pragma unroll
        for (int off = 16; off >= 1; off >>= 1) Z += __shfl_xor(Z, off);
        *slot = e / Z;
      }
    }
    // pump: write batch A to buf^1 (safe, unread), issue batch B into tA
    if (more) {
      writeW(nwf, jS, m, tA);
      loadW(tA, W, n + 1, jS, m + 16);
      if (t < 64) {
        *(float4*)(nxb + t * 16) = xt0;
        *(float4*)(nxb + 1024 + t * 16) = xt1;
      }
    }
    __syncthreads();                    // c visible

    // ---- s pass: B = f16(c_j * x), accumulate into persistent acc ----
#pragma unroll
    for (int q = 0; q < 4; ++q) {
      const int j = w * 4 + q;
      const float cj = *(const float*)(arena + LG + (j * 32 + ((b32 ^ j) & 31)) * 4);
      F16U yf;
      yf.u = uint4{pkh(cj * xw0.x, cj * xw0.y), pkh(cj * xw0.z, cj * xw0.w),
                   pkh(cj * xw1.x, cj * xw1.y), pkh(cj * xw1.z, cj * xw1.w)};
      const f16x8 af = *(const f16x8*)(wf + j * 1024 + l * 16);
      acc[q] = __builtin_amdgcn_mfma_f32_32x32x16_f16(af, yf.f, acc[q], 0, 0, 0);
    }
    if (more) writeW(nwf, jS, m + 16, tA);   // write batch B
    cur ^= 1;
  }
  store_parts(arena, parts, acc, 1.0f, nchunk, b0, t);
}

// stage B: sum NC partials, squash; optionally add previous v (vsum = v0+v1)
__global__ void reduce_squash(const float* __restrict__ parts, int NC,
                              float* __restrict__ out,
                              const float* __restrict__ addprev) {
  const int e = blockIdx.x * 256 + threadIdx.x;
  float s = 0.f;
  for (int c = 0; c < NC; ++c) s += parts[(size_t)c * ELEMS + e];
  float s2 = s * s;
#pragma unroll
  for (int off = 16; off >= 1; off >>= 1) s2 += __shfl_xor(s2, off);
  const float scale = (s2 / (1.0f + s2)) * rsqrtf(s2 + 1e-7f);
  const float val = s * scale;
  out[e] = addprev ? (addprev[e] + val) : val;
}

extern "C" void kernel_launch(void* const* d_in, const int* in_sizes, int n_in,
                              void* d_out, int out_size, void* d_ws, size_t ws_size,
                              hipStream_t stream) {
  const float* x = (const float*)d_in[0];
  const float* W = (const float*)d_in[1];
  float* out = (float*)d_out;

  float* v0 = (float*)d_ws;
  float* vsum = v0 + ELEMS;
  float* parts = vsum + ELEMS;

  int avail = 0;
  if (ws_size / 4 > 2 * (size_t)ELEMS)
    avail = (int)((ws_size / 4 - 2 * (size_t)ELEMS) / ELEMS);
  int NC = avail < 1 ? 1 : (avail > 64 ? 64 : avail);

  const dim3 blk(512);

  caps_pass0_mfma<<<dim3(NC * 4), blk, 0, stream>>>(x, W, parts, NC);
  reduce_squash<<<512, 256, 0, stream>>>(parts, NC, v0, nullptr);

  caps_phase_mfma<<<dim3(NC * 4), blk, 0, stream>>>(x, W, v0, parts, NC);
  reduce_squash<<<512, 256, 0, stream>>>(parts, NC, vsum, v0);  // v0 + v1

  caps_phase_mfma<<<dim3(NC * 4), blk, 0, stream>>>(x, W, vsum, parts, NC);
  reduce_squash<<<512, 256, 0, stream>>>(parts, NC, out, nullptr);
}